// Round 1
// baseline (790.029 us; speedup 1.0000x reference)
//
#include <hip/hip_runtime.h>

typedef __attribute__((ext_vector_type(8))) short short8;
typedef __attribute__((ext_vector_type(4))) float f32x4;

#define B_    8
#define T_    1024
#define C_    2048
#define H_    16
#define HKV_  4
#define HD_   128
#define M_    8192
#define NQKV_ 3072
#define KDIM_ 2048

__device__ __forceinline__ unsigned short f2bf(float f) {
  unsigned u = __float_as_uint(f);
  u += 0x7FFF + ((u >> 16) & 1);
  return (unsigned short)(u >> 16);
}
__device__ __forceinline__ float bf2f(unsigned short h) {
  return __uint_as_float(((unsigned)h) << 16);
}

__device__ __forceinline__ void async16(const unsigned short* g, unsigned short* l) {
  __builtin_amdgcn_global_load_lds(
      (const unsigned int __attribute__((address_space(1)))*)g,
      (unsigned int __attribute__((address_space(3)))*)l,
      16, 0, 0);
}

// ---------------- fp32 -> bf16 straight convert (x) ----------------
__global__ __launch_bounds__(256) void cvt_bf16_kernel(const float* __restrict__ in,
                                                       unsigned short* __restrict__ out) {
  int idx = blockIdx.x * 256 + threadIdx.x;
  float4 v = ((const float4*)in)[idx];
  ushort4 o;
  o.x = f2bf(v.x); o.y = f2bf(v.y); o.z = f2bf(v.z); o.w = f2bf(v.w);
  ((ushort4*)out)[idx] = o;
}

// ------- fp32 [R][Cc] -> bf16 transposed out[c*ldo + r] (weights) -------
__global__ __launch_bounds__(256) void tpose_f32_bf16(const float* __restrict__ in,
                                                      unsigned short* __restrict__ out,
                                                      int Cc, int ldo) {
  __shared__ unsigned short tile[32][33];
  int c0 = blockIdx.x * 32, r0 = blockIdx.y * 32;
  int tx = threadIdx.x, ty = threadIdx.y;
#pragma unroll
  for (int j = 0; j < 4; j++)
    tile[ty + j * 8][tx] = f2bf(in[(size_t)(r0 + ty + j * 8) * Cc + c0 + tx]);
  __syncthreads();
#pragma unroll
  for (int j = 0; j < 4; j++)
    out[(size_t)(c0 + ty + j * 8) * ldo + r0 + tx] = tile[tx][ty + j * 8];
}

// ------- bf16 V-part of qkv -> vT[b][c][t] (per-batch transpose) -------
__global__ __launch_bounds__(256) void vtpose(const unsigned short* __restrict__ qkv,
                                              unsigned short* __restrict__ vt) {
  __shared__ unsigned short tile[32][33];
  int b = blockIdx.z;
  int c0 = blockIdx.x * 32, t0 = blockIdx.y * 32;
  int tx = threadIdx.x, ty = threadIdx.y;
  const unsigned short* src = qkv + (size_t)b * T_ * NQKV_ + 2560;
#pragma unroll
  for (int j = 0; j < 4; j++)
    tile[ty + j * 8][tx] = src[(size_t)(t0 + ty + j * 8) * NQKV_ + c0 + tx];
  __syncthreads();
  unsigned short* dst = vt + (size_t)b * 512 * T_;
#pragma unroll
  for (int j = 0; j < 4; j++)
    dst[(size_t)(c0 + ty + j * 8) * T_ + t0 + tx] = tile[tx][ty + j * 8];
}

// ------- RoPE + relayout: qkv[m][3072] -> qatt[b][h][t][d], katt[b][kh][t][d] -------
__global__ __launch_bounds__(256) void rope_kernel(const unsigned short* __restrict__ qkv,
                                                   const float* __restrict__ sinp,
                                                   const float* __restrict__ cosp,
                                                   unsigned short* __restrict__ qatt,
                                                   unsigned short* __restrict__ katt) {
  int m = blockIdx.x;
  int b = m >> 10, t = m & 1023;
  int tid = threadIdx.x;
  int d = tid & 63;
  const unsigned short* row = qkv + (size_t)m * NQKV_;
  float c0 = cosp[t * 128 + d], s0 = sinp[t * 128 + d];
  float c1 = cosp[t * 128 + d + 64], s1 = sinp[t * 128 + d + 64];
#pragma unroll
  for (int h0 = 0; h0 < 16; h0 += 4) {
    int h = h0 + (tid >> 6);
    float x0 = bf2f(row[h * 128 + d]);
    float x1 = bf2f(row[h * 128 + d + 64]);
    size_t o = ((size_t)(b * 16 + h) * 1024 + t) * 128 + d;
    qatt[o]      = f2bf(x0 * c0 - x1 * s0);
    qatt[o + 64] = f2bf(x1 * c1 + x0 * s1);
  }
  {
    int kh = tid >> 6;
    float x0 = bf2f(row[2048 + kh * 128 + d]);
    float x1 = bf2f(row[2048 + kh * 128 + d + 64]);
    size_t o = ((size_t)(b * 4 + kh) * 1024 + t) * 128 + d;
    katt[o]      = f2bf(x0 * c0 - x1 * s0);
    katt[o + 64] = f2bf(x1 * c1 + x0 * s1);
  }
}

// ------- m97-style GEMM: C[M x N] = A[M x K] * BT[N x K]^T, K=2048 -------
template <int OUTF32>
__global__ __launch_bounds__(256) void gemm_bf16(const unsigned short* __restrict__ A,
                                                 const unsigned short* __restrict__ BT,
                                                 void* __restrict__ Cout, int N) {
  __shared__ unsigned short lA[128 * 32];
  __shared__ unsigned short lB[128 * 32];
  const int K = KDIM_;
  int tid = threadIdx.x;
  int lane = tid & 63;
  int w = tid >> 6;
  int quad = lane >> 4, l16 = lane & 15;
  int bm = blockIdx.y, bn = blockIdx.x;
  const unsigned short* Ab = A + (size_t)bm * 128 * K;
  const unsigned short* Bb = BT + (size_t)bn * 128 * K;
  int i0 = tid, i1 = tid + 256;
  int ra0 = i0 >> 2, ca0 = (i0 & 3) * 8;
  int ra1 = i1 >> 2, ca1 = (i1 & 3) * 8;
  int wm = (w >> 1) * 64, wn = (w & 1) * 64;
  f32x4 acc[4][4] = {};
  for (int k0 = 0; k0 < K; k0 += 32) {
    __syncthreads();
    async16(Ab + (size_t)ra0 * K + k0 + ca0, &lA[i0 * 8]);
    async16(Ab + (size_t)ra1 * K + k0 + ca1, &lA[i1 * 8]);
    async16(Bb + (size_t)ra0 * K + k0 + ca0, &lB[i0 * 8]);
    async16(Bb + (size_t)ra1 * K + k0 + ca1, &lB[i1 * 8]);
    __syncthreads();
    short8 af[4], bfr[4];
#pragma unroll
    for (int mt = 0; mt < 4; mt++)
      af[mt] = *(const short8*)&lA[(wm + mt * 16 + l16) * 32 + quad * 8];
#pragma unroll
    for (int nt = 0; nt < 4; nt++)
      bfr[nt] = *(const short8*)&lB[(wn + nt * 16 + l16) * 32 + quad * 8];
#pragma unroll
    for (int mt = 0; mt < 4; mt++)
#pragma unroll
      for (int nt = 0; nt < 4; nt++)
        acc[mt][nt] = __builtin_amdgcn_mfma_f32_16x16x32_bf16(af[mt], bfr[nt], acc[mt][nt], 0, 0, 0);
  }
#pragma unroll
  for (int mt = 0; mt < 4; mt++) {
#pragma unroll
    for (int nt = 0; nt < 4; nt++) {
      int n = bn * 128 + wn + nt * 16 + l16;
#pragma unroll
      for (int r = 0; r < 4; r++) {
        int m = bm * 128 + wm + mt * 16 + quad * 4 + r;
        if (OUTF32)
          ((float*)Cout)[(size_t)m * N + n] = acc[mt][nt][r];
        else
          ((unsigned short*)Cout)[(size_t)m * N + n] = f2bf(acc[mt][nt][r]);
      }
    }
  }
}

// ------- flash attention: 1 wave / 16 q-rows, Bc=64, causal, GQA -------
__global__ __launch_bounds__(64) void attn_kernel(const unsigned short* __restrict__ Q,
                                                  const unsigned short* __restrict__ Km,
                                                  const unsigned short* __restrict__ Vt,
                                                  unsigned short* __restrict__ Y) {
  __shared__ __align__(16) unsigned short pbuf[16 * 72];  // stride 72 breaks bank aliasing
  int lane = threadIdx.x;
  int quad = lane >> 4, l16 = lane & 15;
  int qt = blockIdx.x, bh = blockIdx.y;
  int b = bh >> 4, h = bh & 15, kh = h & 3;
  int qbase = qt * 16;
  const unsigned short* Qb = Q + ((size_t)bh * T_ + qbase) * 128;
  const unsigned short* Kb = Km + (size_t)(b * 4 + kh) * T_ * 128;
  const unsigned short* Vb = Vt + (size_t)(b * 4 + kh) * 128 * T_;
  short8 qf[4];
#pragma unroll
  for (int ks = 0; ks < 4; ks++)
    qf[ks] = *(const short8*)&Qb[l16 * 128 + ks * 32 + quad * 8];
  f32x4 o[8] = {};
  float m_r[4] = {-1e30f, -1e30f, -1e30f, -1e30f};
  float l_r[4] = {0.f, 0.f, 0.f, 0.f};
  const float sc = 0.12751744690989f;  // log2(e)/sqrt(128)
  int ntile = qt / 4 + 1;
  for (int kt = 0; kt < ntile; kt++) {
    int n0 = kt * 64;
    f32x4 s[4] = {};
#pragma unroll
    for (int ct = 0; ct < 4; ct++) {
#pragma unroll
      for (int ks = 0; ks < 4; ks++) {
        short8 kf = *(const short8*)&Kb[(size_t)(n0 + ct * 16 + l16) * 128 + ks * 32 + quad * 8];
        s[ct] = __builtin_amdgcn_mfma_f32_16x16x32_bf16(qf[ks], kf, s[ct], 0, 0, 0);
      }
    }
#pragma unroll
    for (int ct = 0; ct < 4; ct++)
#pragma unroll
      for (int r = 0; r < 4; r++)
        s[ct][r] *= sc;
    if (kt == ntile - 1) {
#pragma unroll
      for (int ct = 0; ct < 4; ct++) {
        int n = n0 + ct * 16 + l16;
#pragma unroll
        for (int r = 0; r < 4; r++) {
          int q = qbase + quad * 4 + r;
          if (n > q) s[ct][r] = -1e30f;
        }
      }
    }
    float mn[4], alpha[4];
#pragma unroll
    for (int r = 0; r < 4; r++) {
      float v = fmaxf(fmaxf(s[0][r], s[1][r]), fmaxf(s[2][r], s[3][r]));
#pragma unroll
      for (int off = 1; off < 16; off <<= 1)
        v = fmaxf(v, __shfl_xor(v, off));
      mn[r] = fmaxf(m_r[r], v);
      alpha[r] = exp2f(m_r[r] - mn[r]);
      m_r[r] = mn[r];
    }
#pragma unroll
    for (int ct = 0; ct < 4; ct++)
#pragma unroll
      for (int r = 0; r < 4; r++)
        s[ct][r] = exp2f(s[ct][r] - mn[r]);
#pragma unroll
    for (int r = 0; r < 4; r++) {
      float v = s[0][r] + s[1][r] + s[2][r] + s[3][r];
#pragma unroll
      for (int off = 1; off < 16; off <<= 1)
        v += __shfl_xor(v, off);
      l_r[r] = l_r[r] * alpha[r] + v;
    }
#pragma unroll
    for (int dt = 0; dt < 8; dt++)
#pragma unroll
      for (int r = 0; r < 4; r++)
        o[dt][r] *= alpha[r];
    __syncthreads();  // prior iteration's pbuf reads done before overwrite
#pragma unroll
    for (int ct = 0; ct < 4; ct++)
#pragma unroll
      for (int r = 0; r < 4; r++)
        pbuf[(quad * 4 + r) * 72 + ct * 16 + l16] = f2bf(s[ct][r]);
    __syncthreads();  // writes visible before A-layout reads
#pragma unroll
    for (int ks2 = 0; ks2 < 2; ks2++) {
      short8 pa = *(const short8*)&pbuf[l16 * 72 + ks2 * 32 + quad * 8];
#pragma unroll
      for (int dt = 0; dt < 8; dt++) {
        short8 vf = *(const short8*)&Vb[(size_t)(dt * 16 + l16) * T_ + n0 + ks2 * 32 + quad * 8];
        o[dt] = __builtin_amdgcn_mfma_f32_16x16x32_bf16(pa, vf, o[dt], 0, 0, 0);
      }
    }
  }
#pragma unroll
  for (int r = 0; r < 4; r++) {
    int q = qbase + quad * 4 + r;
    float inv = 1.f / l_r[r];
    size_t base = ((size_t)(b * 1024 + q)) * 2048 + h * 128 + l16;
#pragma unroll
    for (int dt = 0; dt < 8; dt++)
      Y[base + dt * 16] = f2bf(o[dt][r] * inv);
  }
}

extern "C" void kernel_launch(void* const* d_in, const int* in_sizes, int n_in,
                              void* d_out, int out_size, void* d_ws, size_t ws_size,
                              hipStream_t stream) {
  const float* x    = (const float*)d_in[0];
  const float* wq   = (const float*)d_in[1];
  const float* wk   = (const float*)d_in[2];
  const float* wv   = (const float*)d_in[3];
  const float* wo   = (const float*)d_in[4];
  const float* sinp = (const float*)d_in[5];
  const float* cosp = (const float*)d_in[6];

  char* ws = (char*)d_ws;
  unsigned short* WCATT = (unsigned short*)(ws);                 // [3072][2048] bf16
  unsigned short* WOT   = (unsigned short*)(ws + 12582912);      // [2048][2048] bf16
  unsigned short* XBF   = (unsigned short*)(ws + 20971520);      // [8192][2048] bf16
  unsigned short* QKV   = (unsigned short*)(ws + 54525952);      // [8192][3072] bf16
  unsigned short* KATT  = (unsigned short*)(ws + 104857600);     // [8*4][1024][128]
  unsigned short* VT    = (unsigned short*)(ws + 113246208);     // [8*4][128][1024]
  unsigned short* QATT  = XBF;  // alias: x_bf16 dead after GEMM1
  unsigned short* Y     = QKV;  // alias: qkv dead after rope+vtpose

  dim3 tb(32, 8);
  cvt_bf16_kernel<<<16384, 256, 0, stream>>>(x, XBF);
  tpose_f32_bf16<<<dim3(64, 64), tb, 0, stream>>>(wq, WCATT, 2048, 2048);
  tpose_f32_bf16<<<dim3(16, 64), tb, 0, stream>>>(wk, WCATT + (size_t)2048 * 2048, 512, 2048);
  tpose_f32_bf16<<<dim3(16, 64), tb, 0, stream>>>(wv, WCATT + (size_t)2560 * 2048, 512, 2048);
  tpose_f32_bf16<<<dim3(64, 64), tb, 0, stream>>>(wo, WOT, 2048, 2048);
  gemm_bf16<0><<<dim3(24, 64), 256, 0, stream>>>(XBF, WCATT, QKV, 3072);
  rope_kernel<<<8192, 256, 0, stream>>>(QKV, sinp, cosp, QATT, KATT);
  vtpose<<<dim3(16, 32, 8), tb, 0, stream>>>(QKV, VT);
  attn_kernel<<<dim3(64, 128), 64, 0, stream>>>(QATT, KATT, VT, Y);
  gemm_bf16<1><<<dim3(16, 64), 256, 0, stream>>>(Y, WOT, d_out, 2048);
}

// Round 2
// 555.899 us; speedup vs baseline: 1.4212x; 1.4212x over previous
//
#include <hip/hip_runtime.h>

typedef __attribute__((ext_vector_type(8))) short short8;
typedef __attribute__((ext_vector_type(4))) float f32x4;

#define B_    8
#define T_    1024
#define C_    2048
#define H_    16
#define HKV_  4
#define HD_   128
#define M_    8192
#define NQKV_ 3072
#define KDIM_ 2048

__device__ __forceinline__ unsigned short f2bf(float f) {
  unsigned u = __float_as_uint(f);
  u += 0x7FFF + ((u >> 16) & 1);
  return (unsigned short)(u >> 16);
}
__device__ __forceinline__ float bf2f(unsigned short h) {
  return __uint_as_float(((unsigned)h) << 16);
}

__device__ __forceinline__ void async16(const unsigned short* g, unsigned short* l) {
  __builtin_amdgcn_global_load_lds(
      (const unsigned int __attribute__((address_space(1)))*)g,
      (unsigned int __attribute__((address_space(3)))*)l,
      16, 0, 0);
}

// ---------------- fp32 -> bf16 straight convert (x) ----------------
__global__ __launch_bounds__(256) void cvt_bf16_kernel(const float* __restrict__ in,
                                                       unsigned short* __restrict__ out) {
  int idx = blockIdx.x * 256 + threadIdx.x;
  float4 v = ((const float4*)in)[idx];
  ushort4 o;
  o.x = f2bf(v.x); o.y = f2bf(v.y); o.z = f2bf(v.z); o.w = f2bf(v.w);
  ((ushort4*)out)[idx] = o;
}

// ------- fp32 [R][Cc] -> bf16 transposed out[c*ldo + r] (weights) -------
__global__ __launch_bounds__(256) void tpose_f32_bf16(const float* __restrict__ in,
                                                      unsigned short* __restrict__ out,
                                                      int Cc, int ldo) {
  __shared__ unsigned short tile[32][33];
  int c0 = blockIdx.x * 32, r0 = blockIdx.y * 32;
  int tx = threadIdx.x, ty = threadIdx.y;
#pragma unroll
  for (int j = 0; j < 4; j++)
    tile[ty + j * 8][tx] = f2bf(in[(size_t)(r0 + ty + j * 8) * Cc + c0 + tx]);
  __syncthreads();
#pragma unroll
  for (int j = 0; j < 4; j++)
    out[(size_t)(c0 + ty + j * 8) * ldo + r0 + tx] = tile[tx][ty + j * 8];
}

// ------- bf16 V-part of qkv -> vT[b][c][t] (per-batch transpose) -------
__global__ __launch_bounds__(256) void vtpose(const unsigned short* __restrict__ qkv,
                                              unsigned short* __restrict__ vt) {
  __shared__ unsigned short tile[32][33];
  int b = blockIdx.z;
  int c0 = blockIdx.x * 32, t0 = blockIdx.y * 32;
  int tx = threadIdx.x, ty = threadIdx.y;
  const unsigned short* src = qkv + (size_t)b * T_ * NQKV_ + 2560;
#pragma unroll
  for (int j = 0; j < 4; j++)
    tile[ty + j * 8][tx] = src[(size_t)(t0 + ty + j * 8) * NQKV_ + c0 + tx];
  __syncthreads();
  unsigned short* dst = vt + (size_t)b * 512 * T_;
#pragma unroll
  for (int j = 0; j < 4; j++)
    dst[(size_t)(c0 + ty + j * 8) * T_ + t0 + tx] = tile[tx][ty + j * 8];
}

// ------- RoPE + relayout: qkv[m][3072] -> qatt[b][h][t][d], katt[b][kh][t][d] -------
__global__ __launch_bounds__(256) void rope_kernel(const unsigned short* __restrict__ qkv,
                                                   const float* __restrict__ sinp,
                                                   const float* __restrict__ cosp,
                                                   unsigned short* __restrict__ qatt,
                                                   unsigned short* __restrict__ katt) {
  int m = blockIdx.x;
  int b = m >> 10, t = m & 1023;
  int tid = threadIdx.x;
  int d = tid & 63;
  const unsigned short* row = qkv + (size_t)m * NQKV_;
  float c0 = cosp[t * 128 + d], s0 = sinp[t * 128 + d];
  float c1 = cosp[t * 128 + d + 64], s1 = sinp[t * 128 + d + 64];
#pragma unroll
  for (int h0 = 0; h0 < 16; h0 += 4) {
    int h = h0 + (tid >> 6);
    float x0 = bf2f(row[h * 128 + d]);
    float x1 = bf2f(row[h * 128 + d + 64]);
    size_t o = ((size_t)(b * 16 + h) * 1024 + t) * 128 + d;
    qatt[o]      = f2bf(x0 * c0 - x1 * s0);
    qatt[o + 64] = f2bf(x1 * c1 + x0 * s1);
  }
  {
    int kh = tid >> 6;
    float x0 = bf2f(row[2048 + kh * 128 + d]);
    float x1 = bf2f(row[2048 + kh * 128 + d + 64]);
    size_t o = ((size_t)(b * 4 + kh) * 1024 + t) * 128 + d;
    katt[o]      = f2bf(x0 * c0 - x1 * s0);
    katt[o + 64] = f2bf(x1 * c1 + x0 * s1);
  }
}

// ------- m97-style GEMM: C[M x N] = A[M x K] * BT[N x K]^T, K=2048 -------
template <int OUTF32>
__global__ __launch_bounds__(256) void gemm_bf16(const unsigned short* __restrict__ A,
                                                 const unsigned short* __restrict__ BT,
                                                 void* __restrict__ Cout, int N) {
  __shared__ unsigned short lA[128 * 32];
  __shared__ unsigned short lB[128 * 32];
  const int K = KDIM_;
  int tid = threadIdx.x;
  int lane = tid & 63;
  int w = tid >> 6;
  int quad = lane >> 4, l16 = lane & 15;
  int bm = blockIdx.y, bn = blockIdx.x;
  const unsigned short* Ab = A + (size_t)bm * 128 * K;
  const unsigned short* Bb = BT + (size_t)bn * 128 * K;
  int i0 = tid, i1 = tid + 256;
  int ra0 = i0 >> 2, ca0 = (i0 & 3) * 8;
  int ra1 = i1 >> 2, ca1 = (i1 & 3) * 8;
  int wm = (w >> 1) * 64, wn = (w & 1) * 64;
  f32x4 acc[4][4] = {};
  for (int k0 = 0; k0 < K; k0 += 32) {
    __syncthreads();
    async16(Ab + (size_t)ra0 * K + k0 + ca0, &lA[i0 * 8]);
    async16(Ab + (size_t)ra1 * K + k0 + ca1, &lA[i1 * 8]);
    async16(Bb + (size_t)ra0 * K + k0 + ca0, &lB[i0 * 8]);
    async16(Bb + (size_t)ra1 * K + k0 + ca1, &lB[i1 * 8]);
    __syncthreads();
    short8 af[4], bfr[4];
#pragma unroll
    for (int mt = 0; mt < 4; mt++)
      af[mt] = *(const short8*)&lA[(wm + mt * 16 + l16) * 32 + quad * 8];
#pragma unroll
    for (int nt = 0; nt < 4; nt++)
      bfr[nt] = *(const short8*)&lB[(wn + nt * 16 + l16) * 32 + quad * 8];
#pragma unroll
    for (int mt = 0; mt < 4; mt++)
#pragma unroll
      for (int nt = 0; nt < 4; nt++)
        acc[mt][nt] = __builtin_amdgcn_mfma_f32_16x16x32_bf16(af[mt], bfr[nt], acc[mt][nt], 0, 0, 0);
  }
#pragma unroll
  for (int mt = 0; mt < 4; mt++) {
#pragma unroll
    for (int nt = 0; nt < 4; nt++) {
      int n = bn * 128 + wn + nt * 16 + l16;
#pragma unroll
      for (int r = 0; r < 4; r++) {
        int m = bm * 128 + wm + mt * 16 + quad * 4 + r;
        if (OUTF32)
          ((float*)Cout)[(size_t)m * N + n] = acc[mt][nt][r];
        else
          ((unsigned short*)Cout)[(size_t)m * N + n] = f2bf(acc[mt][nt][r]);
      }
    }
  }
}

// ------- flash attention v2: 4 waves/block, 64 q-rows, LDS-staged K/V -------
// Block = (b,h, 64-row q tile). Each wave owns 16 q rows. K tile [64][128] and
// V tile [128][64] staged via global_load_lds in BK=32-split layout (same
// ds_read_b128 fragment pattern as the GEMM). P round-trip aliased into lK
// (dead after QK reads; barrier-protected). LDS = 32 KB -> 5 blocks/CU.
__global__ __launch_bounds__(256, 4) void attn_kernel(const unsigned short* __restrict__ Q,
                                                      const unsigned short* __restrict__ Km,
                                                      const unsigned short* __restrict__ Vt,
                                                      unsigned short* __restrict__ Y) {
  __shared__ __align__(16) unsigned short lK[8192];  // [ks 0..3][row 0..63][32]
  __shared__ __align__(16) unsigned short lV[8192];  // [ks2 0..1][d 0..127][32]
  int tid = threadIdx.x;
  int lane = tid & 63, w = tid >> 6;
  int quad = lane >> 4, l16 = lane & 15;
  int qt = 15 - blockIdx.x;  // heavy tiles dispatch first
  int bh = blockIdx.y;
  int b = bh >> 4, h = bh & 15, kh = h & 3;
  int qrow0 = qt * 64 + w * 16;
  const unsigned short* Qb = Q + ((size_t)bh * T_ + qrow0) * 128;
  const unsigned short* Kb = Km + (size_t)(b * 4 + kh) * T_ * 128;
  const unsigned short* Vb = Vt + (size_t)(b * 4 + kh) * 128 * T_;
  short8 qf[4];
#pragma unroll
  for (int ks = 0; ks < 4; ks++)
    qf[ks] = *(const short8*)&Qb[l16 * 128 + ks * 32 + quad * 8];
  f32x4 o[8] = {};
  float m_r[4] = {-1e30f, -1e30f, -1e30f, -1e30f};
  float l_r[4] = {0.f, 0.f, 0.f, 0.f};
  const float sc = 0.12751744690989f;  // log2(e)/sqrt(128)
  unsigned short* pb = &lK[w * 1152];  // per-wave P region, stride 72
  int ntile = qt + 1;
  for (int kt = 0; kt < ntile; kt++) {
    int n0 = kt * 64;
    __syncthreads();  // A: prior iter's lV/P reads done before restage
#pragma unroll
    for (int j = 0; j < 4; j++) {
      int i = tid + j * 256;  // K chunk: ks=i>>8, row=(i>>2)&63, tq=i&3
      async16(Kb + (size_t)(n0 + ((i >> 2) & 63)) * 128 + (i >> 8) * 32 + (i & 3) * 8,
              &lK[i * 8]);
    }
#pragma unroll
    for (int j = 0; j < 4; j++) {
      int i = tid + j * 256;  // V chunk: ks2=i>>9, d=(i>>2)&127, tq=i&3
      async16(Vb + (size_t)((i >> 2) & 127) * T_ + n0 + (i >> 9) * 32 + (i & 3) * 8,
              &lV[i * 8]);
    }
    __syncthreads();  // B: staging complete (vmcnt(0) drain)
    f32x4 s[4] = {};
#pragma unroll
    for (int ct = 0; ct < 4; ct++) {
#pragma unroll
      for (int ks = 0; ks < 4; ks++) {
        short8 kf = *(const short8*)&lK[ks * 2048 + (ct * 16 + l16) * 32 + quad * 8];
        s[ct] = __builtin_amdgcn_mfma_f32_16x16x32_bf16(qf[ks], kf, s[ct], 0, 0, 0);
      }
    }
#pragma unroll
    for (int ct = 0; ct < 4; ct++)
#pragma unroll
      for (int r = 0; r < 4; r++)
        s[ct][r] *= sc;
    if (kt == qt) {  // diagonal tile: causal mask
#pragma unroll
      for (int ct = 0; ct < 4; ct++) {
        int n = n0 + ct * 16 + l16;
#pragma unroll
        for (int r = 0; r < 4; r++) {
          int q = qrow0 + quad * 4 + r;
          if (n > q) s[ct][r] = -1e30f;
        }
      }
    }
    float mn[4], alpha[4];
#pragma unroll
    for (int r = 0; r < 4; r++) {
      float v = fmaxf(fmaxf(s[0][r], s[1][r]), fmaxf(s[2][r], s[3][r]));
#pragma unroll
      for (int off = 1; off < 16; off <<= 1)
        v = fmaxf(v, __shfl_xor(v, off));
      mn[r] = fmaxf(m_r[r], v);
      alpha[r] = exp2f(m_r[r] - mn[r]);
      m_r[r] = mn[r];
    }
#pragma unroll
    for (int ct = 0; ct < 4; ct++)
#pragma unroll
      for (int r = 0; r < 4; r++)
        s[ct][r] = exp2f(s[ct][r] - mn[r]);
#pragma unroll
    for (int r = 0; r < 4; r++) {
      float v = s[0][r] + s[1][r] + s[2][r] + s[3][r];
#pragma unroll
      for (int off = 1; off < 16; off <<= 1)
        v += __shfl_xor(v, off);
      l_r[r] = l_r[r] * alpha[r] + v;
    }
#pragma unroll
    for (int dt = 0; dt < 8; dt++)
#pragma unroll
      for (int r = 0; r < 4; r++)
        o[dt][r] *= alpha[r];
    __syncthreads();  // C: all waves' lK fragment reads done before P overwrite
#pragma unroll
    for (int ct = 0; ct < 4; ct++)
#pragma unroll
      for (int r = 0; r < 4; r++)
        pb[(quad * 4 + r) * 72 + ct * 16 + l16] = f2bf(s[ct][r]);
    __builtin_amdgcn_s_waitcnt(0xC07F);  // lgkmcnt(0): P writes visible to own wave
#pragma unroll
    for (int ks2 = 0; ks2 < 2; ks2++) {
      short8 pa = *(const short8*)&pb[l16 * 72 + ks2 * 32 + quad * 8];
#pragma unroll
      for (int dt = 0; dt < 8; dt++) {
        short8 vf = *(const short8*)&lV[ks2 * 4096 + (dt * 16 + l16) * 32 + quad * 8];
        o[dt] = __builtin_amdgcn_mfma_f32_16x16x32_bf16(pa, vf, o[dt], 0, 0, 0);
      }
    }
  }
#pragma unroll
  for (int r = 0; r < 4; r++) {
    int q = qrow0 + quad * 4 + r;
    float inv = 1.f / l_r[r];
    size_t base = ((size_t)(b * 1024 + q)) * 2048 + h * 128 + l16;
#pragma unroll
    for (int dt = 0; dt < 8; dt++)
      Y[base + dt * 16] = f2bf(o[dt][r] * inv);
  }
}

extern "C" void kernel_launch(void* const* d_in, const int* in_sizes, int n_in,
                              void* d_out, int out_size, void* d_ws, size_t ws_size,
                              hipStream_t stream) {
  const float* x    = (const float*)d_in[0];
  const float* wq   = (const float*)d_in[1];
  const float* wk   = (const float*)d_in[2];
  const float* wv   = (const float*)d_in[3];
  const float* wo   = (const float*)d_in[4];
  const float* sinp = (const float*)d_in[5];
  const float* cosp = (const float*)d_in[6];

  char* ws = (char*)d_ws;
  unsigned short* WCATT = (unsigned short*)(ws);                 // [3072][2048] bf16
  unsigned short* WOT   = (unsigned short*)(ws + 12582912);      // [2048][2048] bf16
  unsigned short* XBF   = (unsigned short*)(ws + 20971520);      // [8192][2048] bf16
  unsigned short* QKV   = (unsigned short*)(ws + 54525952);      // [8192][3072] bf16
  unsigned short* KATT  = (unsigned short*)(ws + 104857600);     // [8*4][1024][128]
  unsigned short* VT    = (unsigned short*)(ws + 113246208);     // [8*4][128][1024]
  unsigned short* QATT  = XBF;  // alias: x_bf16 dead after GEMM1
  unsigned short* Y     = QKV;  // alias: qkv dead after rope+vtpose

  dim3 tb(32, 8);
  cvt_bf16_kernel<<<16384, 256, 0, stream>>>(x, XBF);
  tpose_f32_bf16<<<dim3(64, 64), tb, 0, stream>>>(wq, WCATT, 2048, 2048);
  tpose_f32_bf16<<<dim3(16, 64), tb, 0, stream>>>(wk, WCATT + (size_t)2048 * 2048, 512, 2048);
  tpose_f32_bf16<<<dim3(16, 64), tb, 0, stream>>>(wv, WCATT + (size_t)2560 * 2048, 512, 2048);
  tpose_f32_bf16<<<dim3(64, 64), tb, 0, stream>>>(wo, WOT, 2048, 2048);
  gemm_bf16<0><<<dim3(24, 64), 256, 0, stream>>>(XBF, WCATT, QKV, 3072);
  rope_kernel<<<8192, 256, 0, stream>>>(QKV, sinp, cosp, QATT, KATT);
  vtpose<<<dim3(16, 32, 8), tb, 0, stream>>>(QKV, VT);
  attn_kernel<<<dim3(16, 128), 256, 0, stream>>>(QATT, KATT, VT, Y);
  gemm_bf16<1><<<dim3(16, 64), 256, 0, stream>>>(Y, WOT, d_out, 2048);
}